// Round 1
// baseline (1366.693 us; speedup 1.0000x reference)
//
#include <hip/hip_runtime.h>
#include <stdint.h>

// Correlation1dCost: out[b,d,y,x] = leaky_relu_0.1( sum_c f1[b,c,y,x]*f2[b,c,y,x+d-47] )
// B=8, C=128, H=128, W=256, ND=48. Zero contribution where x+d-47 < 0.
//
// R5: latency-pipeline fix. R4 was latency-serialized (all counters <30%):
// the read asm held lgkmcnt(0) + "memory" clobber, forcing a full LDS
// round-trip stall per channel and blocking all cross-channel overlap.
// R5: (a) q-register double buffer: issue ch cc+1's 4 ds_read_b128, wait
// lgkmcnt(4) (counted, dep-tied via "+v") while ch cc's 48 FMAs run;
// (b) no memory clobber on reads -> f1 loads pipelined 1 channel ahead;
// (c) LDS double buffer: stage tile it+1 during tile it, ONE barrier per
// tile (8 vs 16), staging globals issued before the compute phase;
// (d) waves_per_eu(4) pins VGPR<=128 so all 4 blocks/CU stay resident.

typedef float f32x4 __attribute__((ext_vector_type(4)));

#define Bn 8
#define Cn 128
#define Hn 128
#define Wn 256
#define ND 48
#define F2Q 76           // float4s per s2 row: 12 pad (words -48..-1) + 64 data
#define ROWB (F2Q * 16)  // 1216 B per channel row
#define CC 16            // channels staged per tile
#define NIT (Cn / CC)    // 8 tiles
#define TD 12            // d's per thread
#define BUFB (CC * ROWB) // 19456 B per LDS buffer

__device__ __forceinline__ unsigned lds_off(const void* p) {
    return (unsigned)(uintptr_t)p;
}

// 4 contiguous b128 reads, NO waitcnt, NO memory clobber (ordering vs the
// volatile write asm is preserved by volatile-volatile program order).
#define DS_READ4(q, off)                                                \
    asm volatile("ds_read_b128 %0, %4\n\t"                              \
                 "ds_read_b128 %1, %4 offset:16\n\t"                    \
                 "ds_read_b128 %2, %4 offset:32\n\t"                    \
                 "ds_read_b128 %3, %4 offset:48"                        \
                 : "=&v"(q[0]), "=&v"(q[1]), "=&v"(q[2]), "=&v"(q[3])   \
                 : "v"(off))

// Counted wait tied to the q registers it guards ("+v" makes every later
// use of q depend on this asm -> FMAs cannot be hoisted above the wait).
#define WAITQ(q, n)                                                     \
    asm volatile("s_waitcnt lgkmcnt(" #n ")"                            \
                 : "+v"(q[0]), "+v"(q[1]), "+v"(q[2]), "+v"(q[3]))

__device__ __forceinline__ void lds_write_b128(unsigned off, f32x4 v) {
    asm volatile("ds_write_b128 %0, %1" :: "v"(off), "v"(v) : "memory");
}

// 4 staging writes (rows j, j+4, j+8, j+12) from one base VGPR.
// Row stride 4*ROWB = 4864 B; all offsets < 64 KiB.
#define DS_WRITE4(off, g)                                               \
    asm volatile("ds_write_b128 %0, %1\n\t"                             \
                 "ds_write_b128 %0, %2 offset:4864\n\t"                 \
                 "ds_write_b128 %0, %3 offset:9728\n\t"                 \
                 "ds_write_b128 %0, %4 offset:14592"                    \
                 :: "v"(off), "v"(g[0]), "v"(g[1]), "v"(g[2]), "v"(g[3]) \
                 : "memory")

__global__ __launch_bounds__(256)
__attribute__((amdgpu_waves_per_eu(4)))
void corr1d_kernel(const float* __restrict__ f1,
                   const float* __restrict__ f2,
                   float* __restrict__ out)
{
    __shared__ f32x4 s2v[2][CC][F2Q];   // 38912 B -> 4 blocks/CU

    const int y   = blockIdx.x;      // 0..127
    const int b   = blockIdx.y;      // 0..7
    const int tid = threadIdx.x;
    const int i   = tid & 63;        // x-group: x = 4*i .. 4*i+3
    const int j   = tid >> 6;        // d-group: d = 12*j .. 12*j+11

    const unsigned s2b   = lds_off(&s2v[0][0][0]);
    const unsigned offq0 = s2b + (unsigned)((i + 3 * j) * 16);  // q window base

    const size_t chw = (size_t)Hn * Wn;
    const float* f1base = f1 + ((size_t)b * Cn * Hn + y) * Wn;
    const float* f2base = f2 + ((size_t)b * Cn * Hn + y) * Wn;

    // staging: rows j+4t, data word 4*sp (pad = first 12 quads of each row)
    const int sp = tid & 63;
    const unsigned sw0 = s2b + (unsigned)((j * F2Q + 12 + sp) * 16);

    // ---- zero the always-zero pad region of BOTH buffers once ----
    if ((tid & 15) < 12) {
        f32x4 z = {0.f, 0.f, 0.f, 0.f};
        unsigned zoff = s2b + (unsigned)(((tid >> 4) * F2Q + (tid & 15)) * 16);
        lds_write_b128(zoff, z);
        lds_write_b128(zoff + BUFB, z);
    }

    float acc[4][TD];
    #pragma unroll
    for (int xr = 0; xr < 4; ++xr)
        #pragma unroll
        for (int dr = 0; dr < TD; ++dr) acc[xr][dr] = 0.f;

    // ---- prefetch + stage tile 0 into buffer 0 ----
    f32x4 g[4];
    #pragma unroll
    for (int t = 0; t < 4; ++t)
        g[t] = *(const f32x4*)(f2base + (size_t)(j + 4 * t) * chw + sp * 4);
    DS_WRITE4(sw0, g);     // compiler inserts vmcnt wait for g
    __syncthreads();

    for (int it = 0; it < NIT; ++it) {
        const unsigned pb  = (unsigned)(it & 1) * BUFB;   // read buffer base
        const unsigned pbn = BUFB - pb;                   // write buffer base

        // issue next tile's global loads now; they land during compute
        if (it + 1 < NIT) {
            #pragma unroll
            for (int t = 0; t < 4; ++t)
                g[t] = *(const f32x4*)(f2base +
                        (size_t)((it + 1) * CC + j + 4 * t) * chw + sp * 4);
        }

        // ---- compute 16 channels, LDS reads pipelined 1 channel deep ----
        const float* f1p = f1base + (size_t)(it * CC) * chw + i * 4;
        const unsigned roff = offq0 + pb;

        f32x4 q[2][4];
        f32x4 av[2];
        DS_READ4(q[0], roff);
        av[0] = *(const f32x4*)(f1p);

        #pragma unroll
        for (int cc = 0; cc < CC; ++cc) {
            const int cur = cc & 1, nxt = cur ^ 1;
            if (cc + 1 < CC) {
                DS_READ4(q[nxt], roff + (unsigned)((cc + 1) * ROWB));
                av[nxt] = *(const f32x4*)(f1p + (size_t)(cc + 1) * chw);
                WAITQ(q[cur], 4);   // q[cur] ready; q[nxt]'s 4 stay in flight
            } else {
                WAITQ(q[cur], 0);
            }
            const float a0 = av[cur][0], a1 = av[cur][1],
                        a2 = av[cur][2], a3 = av[cur][3];
            float qq[16] = {q[cur][0][0], q[cur][0][1], q[cur][0][2], q[cur][0][3],
                            q[cur][1][0], q[cur][1][1], q[cur][1][2], q[cur][1][3],
                            q[cur][2][0], q[cur][2][1], q[cur][2][2], q[cur][2][3],
                            q[cur][3][0], q[cur][3][1], q[cur][3][2], q[cur][3][3]};
            // out x = 4i+xr, d = 12j+dr -> buffer word 4i+12j + (xr+dr+1)
            #pragma unroll
            for (int dr = 0; dr < TD; ++dr) {
                acc[0][dr] += a0 * qq[dr + 1];
                acc[1][dr] += a1 * qq[dr + 2];
                acc[2][dr] += a2 * qq[dr + 3];
                acc[3][dr] += a3 * qq[dr + 4];
            }
        }

        // ---- stage tile it+1 into the other buffer, one barrier per tile ----
        if (it + 1 < NIT) {
            DS_WRITE4(sw0 + pbn, g);   // vmcnt wait auto-inserted for g
            __syncthreads();
        }
    }

    // ---- epilogue: leaky_relu + float4 stores (contiguous per wave) ----
    #pragma unroll
    for (int dr = 0; dr < TD; ++dr) {
        int d = j * TD + dr;
        float vx[4];
        #pragma unroll
        for (int xr = 0; xr < 4; ++xr) {
            float t = acc[xr][dr];
            vx[xr] = t >= 0.f ? t : 0.1f * t;
        }
        float4 v = make_float4(vx[0], vx[1], vx[2], vx[3]);
        *(float4*)(out + (((size_t)(b * ND + d) * Hn + y) * Wn + i * 4)) = v;
    }
}

extern "C" void kernel_launch(void* const* d_in, const int* in_sizes, int n_in,
                              void* d_out, int out_size, void* d_ws, size_t ws_size,
                              hipStream_t stream) {
    const float* feat1 = (const float*)d_in[0];
    const float* feat2 = (const float*)d_in[1];
    float* out = (float*)d_out;
    dim3 grid(Hn, Bn);   // blockIdx.x = y, blockIdx.y = b
    dim3 block(256);
    corr1d_kernel<<<grid, block, 0, stream>>>(feat1, feat2, out);
}

// Round 2
// 749.535 us; speedup vs baseline: 1.8234x; 1.8234x over previous
//
#include <hip/hip_runtime.h>
#include <stdint.h>

// Correlation1dCost: out[b,d,y,x] = leaky_relu_0.1( sum_c f1[b,c,y,x]*f2[b,c,y,x+d-47] )
// B=8, C=128, H=128, W=256, ND=48. Zero contribution where x+d-47 < 0.
//
// R6: R5's pipeline, spill-free. R5 put the q double-buffer in runtime-
// indexed arrays (q[2][4] indexed by cc&1) -> demoted to scratch (rule #20):
// FETCH 131MB->1.56GB, WRITE 49MB->2.87GB, VALUBusy 3%. R6 hand-unrolls the
// channel loop 2x with NAMED register sets qA/qB, avA/avB -- every register
// index compile-time. Pipeline semantics unchanged:
//   even ch: issue qB reads + f1(cc+1), waitcnt lgkmcnt(4), FMA on qA
//   odd  ch: issue qA reads + f1(cc+2), waitcnt lgkmcnt(4), FMA on qB
// LDS double buffer, ONE barrier per tile; staging globals issued before
// the compute phase. waves_per_eu back to (2,4) so regalloc has room.

typedef float f32x4 __attribute__((ext_vector_type(4)));

#define Bn 8
#define Cn 128
#define Hn 128
#define Wn 256
#define ND 48
#define F2Q 76           // float4s per s2 row: 12 pad (words -48..-1) + 64 data
#define ROWB (F2Q * 16)  // 1216 B per channel row
#define CC 16            // channels staged per tile
#define NIT (Cn / CC)    // 8 tiles
#define TD 12            // d's per thread
#define BUFB (CC * ROWB) // 19456 B per LDS buffer

__device__ __forceinline__ unsigned lds_off(const void* p) {
    return (unsigned)(uintptr_t)p;
}

// 4 contiguous b128 reads, NO waitcnt, NO memory clobber (ordering vs the
// volatile write asm / barriers is preserved by volatile program order).
#define DS_READ4(q0, q1, q2, q3, off)                                   \
    asm volatile("ds_read_b128 %0, %4\n\t"                              \
                 "ds_read_b128 %1, %4 offset:16\n\t"                    \
                 "ds_read_b128 %2, %4 offset:32\n\t"                    \
                 "ds_read_b128 %3, %4 offset:48"                        \
                 : "=&v"(q0), "=&v"(q1), "=&v"(q2), "=&v"(q3)           \
                 : "v"(off))

// Counted wait tied to the registers it guards ("+v" makes every later
// use of q depend on this asm -> FMAs cannot be hoisted above the wait).
#define WAITQ(q0, q1, q2, q3, n)                                        \
    asm volatile("s_waitcnt lgkmcnt(" #n ")"                            \
                 : "+v"(q0), "+v"(q1), "+v"(q2), "+v"(q3))

__device__ __forceinline__ void lds_write_b128(unsigned off, f32x4 v) {
    asm volatile("ds_write_b128 %0, %1" :: "v"(off), "v"(v) : "memory");
}

// 4 staging writes (rows j, j+4, j+8, j+12) from one base VGPR.
// Row stride 4*ROWB = 4864 B; all offsets < 64 KiB.
#define DS_WRITE4(off, g)                                               \
    asm volatile("ds_write_b128 %0, %1\n\t"                             \
                 "ds_write_b128 %0, %2 offset:4864\n\t"                 \
                 "ds_write_b128 %0, %3 offset:9728\n\t"                 \
                 "ds_write_b128 %0, %4 offset:14592"                    \
                 :: "v"(off), "v"(g[0]), "v"(g[1]), "v"(g[2]), "v"(g[3]) \
                 : "memory")

// 48 FMAs for one channel. qq[] has only compile-time indices (SROA-safe,
// same pattern as the 143us R4 kernel).
#define FMA_CH(av, p0, p1, p2, p3)                                      \
    do {                                                                \
        const float a0 = (av)[0], a1 = (av)[1], a2 = (av)[2], a3 = (av)[3]; \
        float qq[16] = {(p0)[0], (p0)[1], (p0)[2], (p0)[3],             \
                        (p1)[0], (p1)[1], (p1)[2], (p1)[3],             \
                        (p2)[0], (p2)[1], (p2)[2], (p2)[3],             \
                        (p3)[0], (p3)[1], (p3)[2], (p3)[3]};            \
        _Pragma("unroll")                                               \
        for (int dr = 0; dr < TD; ++dr) {                               \
            acc[0][dr] += a0 * qq[dr + 1];                              \
            acc[1][dr] += a1 * qq[dr + 2];                              \
            acc[2][dr] += a2 * qq[dr + 3];                              \
            acc[3][dr] += a3 * qq[dr + 4];                              \
        }                                                               \
    } while (0)

__global__ __launch_bounds__(256)
__attribute__((amdgpu_waves_per_eu(2, 4)))
void corr1d_kernel(const float* __restrict__ f1,
                   const float* __restrict__ f2,
                   float* __restrict__ out)
{
    __shared__ f32x4 s2v[2][CC][F2Q];   // 38912 B

    const int y   = blockIdx.x;      // 0..127
    const int b   = blockIdx.y;      // 0..7
    const int tid = threadIdx.x;
    const int i   = tid & 63;        // x-group: x = 4*i .. 4*i+3
    const int j   = tid >> 6;        // d-group: d = 12*j .. 12*j+11

    const unsigned s2b   = lds_off(&s2v[0][0][0]);
    const unsigned offq0 = s2b + (unsigned)((i + 3 * j) * 16);  // q window base

    const size_t chw = (size_t)Hn * Wn;
    const float* f1base = f1 + ((size_t)b * Cn * Hn + y) * Wn;
    const float* f2base = f2 + ((size_t)b * Cn * Hn + y) * Wn;

    // staging: rows j+4t, data word 4*sp (pad = first 12 quads of each row)
    const int sp = tid & 63;
    const unsigned sw0 = s2b + (unsigned)((j * F2Q + 12 + sp) * 16);

    // ---- zero the always-zero pad region of BOTH buffers once ----
    if ((tid & 15) < 12) {
        f32x4 z = {0.f, 0.f, 0.f, 0.f};
        unsigned zoff = s2b + (unsigned)(((tid >> 4) * F2Q + (tid & 15)) * 16);
        lds_write_b128(zoff, z);
        lds_write_b128(zoff + BUFB, z);
    }

    float acc[4][TD];
    #pragma unroll
    for (int xr = 0; xr < 4; ++xr)
        #pragma unroll
        for (int dr = 0; dr < TD; ++dr) acc[xr][dr] = 0.f;

    // ---- prefetch + stage tile 0 into buffer 0 ----
    f32x4 g[4];
    #pragma unroll
    for (int t = 0; t < 4; ++t)
        g[t] = *(const f32x4*)(f2base + (size_t)(j + 4 * t) * chw + sp * 4);
    DS_WRITE4(sw0, g);     // compiler inserts vmcnt wait for g
    __syncthreads();

    for (int it = 0; it < NIT; ++it) {
        const unsigned pb  = (unsigned)(it & 1) * BUFB;   // read buffer base
        const unsigned pbn = BUFB - pb;                   // write buffer base

        // issue next tile's global loads now; they land during compute
        if (it + 1 < NIT) {
            #pragma unroll
            for (int t = 0; t < 4; ++t)
                g[t] = *(const f32x4*)(f2base +
                        (size_t)((it + 1) * CC + j + 4 * t) * chw + sp * 4);
        }

        // ---- compute 16 channels, reads pipelined 1 channel deep,
        //      hand-unrolled x2 with NAMED register sets (no runtime idx) ----
        const float* f1p = f1base + (size_t)(it * CC) * chw + i * 4;
        const unsigned roff = offq0 + pb;

        f32x4 qA0, qA1, qA2, qA3, qB0, qB1, qB2, qB3;
        f32x4 avA, avB;
        DS_READ4(qA0, qA1, qA2, qA3, roff);
        avA = *(const f32x4*)(f1p);

        #pragma unroll
        for (int cc = 0; cc < CC; cc += 2) {
            // even channel cc: prefetch cc+1 into B, compute A
            DS_READ4(qB0, qB1, qB2, qB3, roff + (unsigned)((cc + 1) * ROWB));
            avB = *(const f32x4*)(f1p + (size_t)(cc + 1) * chw);
            WAITQ(qA0, qA1, qA2, qA3, 4);   // qA ready; qB's 4 in flight
            FMA_CH(avA, qA0, qA1, qA2, qA3);

            // odd channel cc+1: prefetch cc+2 into A (if any), compute B
            if (cc + 2 < CC) {
                DS_READ4(qA0, qA1, qA2, qA3, roff + (unsigned)((cc + 2) * ROWB));
                avA = *(const f32x4*)(f1p + (size_t)(cc + 2) * chw);
                WAITQ(qB0, qB1, qB2, qB3, 4);
            } else {
                WAITQ(qB0, qB1, qB2, qB3, 0);   // drain before staging
            }
            FMA_CH(avB, qB0, qB1, qB2, qB3);
        }

        // ---- stage tile it+1 into the other buffer, one barrier per tile ----
        if (it + 1 < NIT) {
            DS_WRITE4(sw0 + pbn, g);   // vmcnt wait auto-inserted for g
            __syncthreads();
        }
    }

    // ---- epilogue: leaky_relu + float4 stores (contiguous per wave) ----
    #pragma unroll
    for (int dr = 0; dr < TD; ++dr) {
        int d = j * TD + dr;
        float vx[4];
        #pragma unroll
        for (int xr = 0; xr < 4; ++xr) {
            float t = acc[xr][dr];
            vx[xr] = t >= 0.f ? t : 0.1f * t;
        }
        float4 v = make_float4(vx[0], vx[1], vx[2], vx[3]);
        *(float4*)(out + (((size_t)(b * ND + d) * Hn + y) * Wn + i * 4)) = v;
    }
}

extern "C" void kernel_launch(void* const* d_in, const int* in_sizes, int n_in,
                              void* d_out, int out_size, void* d_ws, size_t ws_size,
                              hipStream_t stream) {
    const float* feat1 = (const float*)d_in[0];
    const float* feat2 = (const float*)d_in[1];
    float* out = (float*)d_out;
    dim3 grid(Hn, Bn);   // blockIdx.x = y, blockIdx.y = b
    dim3 block(256);
    corr1d_kernel<<<grid, block, 0, stream>>>(feat1, feat2, out);
}

// Round 4
// 303.094 us; speedup vs baseline: 4.5091x; 2.4729x over previous
//
#include <hip/hip_runtime.h>
#include <stdint.h>

// Correlation1dCost: out[b,d,y,x] = leaky_relu_0.1( sum_c f1[b,c,y,x]*f2[b,c,y,x+d-47] )
// B=8, C=128, H=128, W=256, ND=48. Zero contribution where x+d-47 < 0.
//
// R8 == R7 resubmitted (round 3 died in container-acquire infra, kernel
// never ran). Rationale unchanged:
// R5/R6 drowned in scratch traffic (WRITE_SIZE 2.9GB/1.3GB vs 49MB output):
// the register-staged f2 prefetch (g[4] live across the whole compute phase
// with a pending-vmcnt tie) pushed live state past the budget. R7/R8 replace
// register staging with __builtin_amdgcn_global_load_lds (direct HBM->LDS
// DMA, no VGPRs, no ds_write, no clobber): staging for tile it+1 is issued
// at the top of tile it and drained by the vmcnt(0) __syncthreads already
// emits. ONE barrier per tile. Compute keeps R6's hand-unrolled qA/qB
// double-buffer with counted lgkmcnt(4) waits (dep-tied via "+v").
// No waves_per_eu attr; expected ~105 VGPR -> 4 waves/SIMD, 4 blocks/CU.

typedef float f32x4 __attribute__((ext_vector_type(4)));

#define Bn 8
#define Cn 128
#define Hn 128
#define Wn 256
#define ND 48
#define F2Q 76           // float4s per s2 row: 12 pad (words -48..-1) + 64 data
#define ROWB (F2Q * 16)  // 1216 B per channel row
#define CC 16            // channels staged per tile
#define NIT (Cn / CC)    // 8 tiles
#define TD 12            // d's per thread
#define BUFB (CC * ROWB) // 19456 B per LDS buffer

__device__ __forceinline__ unsigned lds_off(const void* p) {
    return (unsigned)(uintptr_t)p;
}

// 4 contiguous b128 reads, NO waitcnt, NO memory clobber (ordering vs
// barriers preserved by volatile program order).
#define DS_READ4(q0, q1, q2, q3, off)                                   \
    asm volatile("ds_read_b128 %0, %4\n\t"                              \
                 "ds_read_b128 %1, %4 offset:16\n\t"                    \
                 "ds_read_b128 %2, %4 offset:32\n\t"                    \
                 "ds_read_b128 %3, %4 offset:48"                        \
                 : "=&v"(q0), "=&v"(q1), "=&v"(q2), "=&v"(q3)           \
                 : "v"(off))

// Counted wait tied to the registers it guards ("+v" makes every later
// use of q depend on this asm -> FMAs cannot be hoisted above the wait).
#define WAITQ(q0, q1, q2, q3, n)                                        \
    asm volatile("s_waitcnt lgkmcnt(" #n ")"                            \
                 : "+v"(q0), "+v"(q1), "+v"(q2), "+v"(q3))

__device__ __forceinline__ void lds_write_b128(unsigned off, f32x4 v) {
    asm volatile("ds_write_b128 %0, %1" :: "v"(off), "v"(v) : "memory");
}

// Direct HBM->LDS DMA, 16B per lane. Dest must be wave-uniform base +
// lane*16 (our staging layout satisfies this: row base + sp*16, sp = lane).
__device__ __forceinline__ void gload_lds16(const float* g, char* lds) {
    __builtin_amdgcn_global_load_lds(
        (const __attribute__((address_space(1))) void*)g,
        (__attribute__((address_space(3))) void*)lds,
        16, 0, 0);
}

// 48 FMAs for one channel. qq[] has only compile-time indices.
#define FMA_CH(av, p0, p1, p2, p3)                                      \
    do {                                                                \
        const float a0 = (av)[0], a1 = (av)[1], a2 = (av)[2], a3 = (av)[3]; \
        float qq[16] = {(p0)[0], (p0)[1], (p0)[2], (p0)[3],             \
                        (p1)[0], (p1)[1], (p1)[2], (p1)[3],             \
                        (p2)[0], (p2)[1], (p2)[2], (p2)[3],             \
                        (p3)[0], (p3)[1], (p3)[2], (p3)[3]};            \
        _Pragma("unroll")                                               \
        for (int dr = 0; dr < TD; ++dr) {                               \
            acc[0][dr] += a0 * qq[dr + 1];                              \
            acc[1][dr] += a1 * qq[dr + 2];                              \
            acc[2][dr] += a2 * qq[dr + 3];                              \
            acc[3][dr] += a3 * qq[dr + 4];                              \
        }                                                               \
    } while (0)

__global__ __launch_bounds__(256)
void corr1d_kernel(const float* __restrict__ f1,
                   const float* __restrict__ f2,
                   float* __restrict__ out)
{
    __shared__ f32x4 s2v[2][CC][F2Q];   // 38912 B -> 4 blocks/CU by LDS

    const int y   = blockIdx.x;      // 0..127
    const int b   = blockIdx.y;      // 0..7
    const int tid = threadIdx.x;
    const int i   = tid & 63;        // x-group: x = 4*i .. 4*i+3
    const int j   = tid >> 6;        // d-group: d = 12*j .. 12*j+11

    char* s2c = (char*)&s2v[0][0][0];
    const unsigned s2b   = lds_off(s2c);
    const unsigned offq0 = s2b + (unsigned)((i + 3 * j) * 16);  // q window base

    const size_t chw = (size_t)Hn * Wn;
    const float* f1base = f1 + ((size_t)b * Cn * Hn + y) * Wn;
    const float* f2base = f2 + ((size_t)b * Cn * Hn + y) * Wn;

    const int sp = tid & 63;         // lane id; data word 4*sp of the row

    // ---- zero the always-zero pad region of BOTH buffers once ----
    if ((tid & 15) < 12) {
        f32x4 z = {0.f, 0.f, 0.f, 0.f};
        unsigned zoff = s2b + (unsigned)(((tid >> 4) * F2Q + (tid & 15)) * 16);
        lds_write_b128(zoff, z);
        lds_write_b128(zoff + BUFB, z);
    }

    float acc[4][TD];
    #pragma unroll
    for (int xr = 0; xr < 4; ++xr)
        #pragma unroll
        for (int dr = 0; dr < TD; ++dr) acc[xr][dr] = 0.f;

    // ---- stage tile 0 into buffer 0 (async DMA) ----
    #pragma unroll
    for (int t = 0; t < 4; ++t) {
        const int r = j + 4 * t;     // wave-uniform row
        gload_lds16(f2base + (size_t)r * chw + sp * 4,
                    s2c + (size_t)(r * F2Q + 12 + sp) * 16);
    }
    __syncthreads();                 // drains vmcnt(0): tile 0 resident

    for (int it = 0; it < NIT; ++it) {
        const unsigned pb  = (unsigned)(it & 1) * BUFB;   // read buffer base
        const unsigned pbn = BUFB - pb;                    // write buffer base

        // issue next tile's DMA now; lands any time before the barrier.
        // buf[pbn] was last READ in tile it-1, all waves past that barrier.
        if (it + 1 < NIT) {
            #pragma unroll
            for (int t = 0; t < 4; ++t) {
                const int r = j + 4 * t;
                gload_lds16(f2base + (size_t)((it + 1) * CC + r) * chw + sp * 4,
                            s2c + pbn + (size_t)(r * F2Q + 12 + sp) * 16);
            }
        }

        // ---- compute 16 channels, reads pipelined 1 channel deep,
        //      hand-unrolled x2 with NAMED register sets (no runtime idx) ----
        const float* f1p = f1base + (size_t)(it * CC) * chw + i * 4;
        const unsigned roff = offq0 + pb;

        f32x4 qA0, qA1, qA2, qA3, qB0, qB1, qB2, qB3;
        f32x4 avA, avB;
        DS_READ4(qA0, qA1, qA2, qA3, roff);
        avA = *(const f32x4*)(f1p);

        #pragma unroll
        for (int cc = 0; cc < CC; cc += 2) {
            // even channel cc: prefetch cc+1 into B, compute A
            DS_READ4(qB0, qB1, qB2, qB3, roff + (unsigned)((cc + 1) * ROWB));
            avB = *(const f32x4*)(f1p + (size_t)(cc + 1) * chw);
            WAITQ(qA0, qA1, qA2, qA3, 4);   // qA ready; qB's 4 in flight
            FMA_CH(avA, qA0, qA1, qA2, qA3);

            // odd channel cc+1: prefetch cc+2 into A (if any), compute B
            if (cc + 2 < CC) {
                DS_READ4(qA0, qA1, qA2, qA3, roff + (unsigned)((cc + 2) * ROWB));
                avA = *(const f32x4*)(f1p + (size_t)(cc + 2) * chw);
                WAITQ(qB0, qB1, qB2, qB3, 4);
            } else {
                WAITQ(qB0, qB1, qB2, qB3, 0);   // drain last channel's reads
            }
            FMA_CH(avB, qB0, qB1, qB2, qB3);
        }

        // one barrier per tile: waits vmcnt(0) (staging DMA landed) and
        // gates buffer swap (all waves done reading buf[pb]).
        __syncthreads();
    }

    // ---- epilogue: leaky_relu + float4 stores (contiguous per wave) ----
    #pragma unroll
    for (int dr = 0; dr < TD; ++dr) {
        int d = j * TD + dr;
        float vx[4];
        #pragma unroll
        for (int xr = 0; xr < 4; ++xr) {
            float t = acc[xr][dr];
            vx[xr] = t >= 0.f ? t : 0.1f * t;
        }
        float4 v = make_float4(vx[0], vx[1], vx[2], vx[3]);
        *(float4*)(out + (((size_t)(b * ND + d) * Hn + y) * Wn + i * 4)) = v;
    }
}

extern "C" void kernel_launch(void* const* d_in, const int* in_sizes, int n_in,
                              void* d_out, int out_size, void* d_ws, size_t ws_size,
                              hipStream_t stream) {
    const float* feat1 = (const float*)d_in[0];
    const float* feat2 = (const float*)d_in[1];
    float* out = (float*)d_out;
    dim3 grid(Hn, Bn);   // blockIdx.x = y, blockIdx.y = b
    dim3 block(256);
    corr1d_kernel<<<grid, block, 0, stream>>>(feat1, feat2, out);
}